// Round 1
// baseline (357.250 us; speedup 1.0000x reference)
//
#include <hip/hip_runtime.h>
#include <math.h>

#define BB 8
#define SS 4096
#define HH 1024
#define ROWS (BB * HH)   // 8192
#define KTOP 8

// Sorted-descending top-8 insert; strict > keeps earlier (lower s) on ties,
// matching lax.top_k's lowest-index tie-break.
#define INSERT8(TS, TV, SCV, VALV) do {                                   \
    if ((SCV) > TS[7]) {                                                  \
      TS[7] = (SCV); TV[7] = (VALV);                                      \
      _Pragma("unroll")                                                   \
      for (int _i = 7; _i > 0; --_i) {                                    \
        if (TS[_i] > TS[_i - 1]) {                                        \
          float _t = TS[_i]; TS[_i] = TS[_i - 1]; TS[_i - 1] = _t;        \
          float _v = TV[_i]; TV[_i] = TV[_i - 1]; TV[_i - 1] = _v;        \
        }                                                                 \
      }                                                                   \
    }                                                                     \
  } while (0)

// Kernel 1: per-(row, s-chunk) partial top-8 of log(relu(h)) + gumbel.
// grid (NS, 32); block 256 threads = 256 rows (one h-block of one b).
// pairs layout: [(chunk*8 + j) * ROWS + r]  (coalesced write & merge-read)
__global__ __launch_bounds__(256) void topk_partial(
    const float* __restrict__ hidden, const float* __restrict__ gumbel,
    float2* __restrict__ pairs, int SC) {
  __shared__ float lds_g[256 * 17];   // [row][si], stride 17 -> conflict-free
  __shared__ float lds_h[16 * 256];   // [si][h], conflict-free

  const int tid = threadIdx.x;
  const int sc  = blockIdx.x;
  const int rb  = blockIdx.y;
  const int r   = rb * 256 + tid;
  const int b   = rb >> 2;            // 256 rows never straddle a b boundary
  const int h0  = (rb & 3) << 8;
  const int s0  = sc * SC;
  const int lane = tid & 63;

  float ts[KTOP], tv[KTOP];
#pragma unroll
  for (int i = 0; i < KTOP; ++i) { ts[i] = -INFINITY; tv[i] = 0.0f; }

  for (int ss = 0; ss < SC; ss += 16) {
    // stage gumbel[r0..r0+255][s0+ss .. +15]: 4 lanes x 16B = 64B per row
    {
      const int si4 = tid & 3;
      const int rl  = tid >> 2;
#pragma unroll
      for (int p = 0; p < 4; ++p) {
        const int row = p * 64 + rl;
        const float4 g4 = *(const float4*)&gumbel[
            (size_t)(rb * 256 + row) * SS + (s0 + ss) + si4 * 4];
        lds_g[row * 17 + si4 * 4 + 0] = g4.x;
        lds_g[row * 17 + si4 * 4 + 1] = g4.y;
        lds_g[row * 17 + si4 * 4 + 2] = g4.z;
        lds_g[row * 17 + si4 * 4 + 3] = g4.w;
      }
    }
    // stage hidden[b][s..s+15][h0..h0+255]: 1KB contiguous per wave instr
    {
      const int srow = tid >> 6;
#pragma unroll
      for (int p = 0; p < 4; ++p) {
        const int si = p * 4 + srow;
        const float4 h4 = *(const float4*)&hidden[
            ((size_t)b * SS + (s0 + ss + si)) * HH + h0 + lane * 4];
        *(float4*)&lds_h[si * 256 + lane * 4] = h4;
      }
    }
    __syncthreads();
#pragma unroll 4
    for (int si = 0; si < 16; ++si) {
      const float t   = fmaxf(lds_h[si * 256 + tid], 0.0f);
      const float g   = lds_g[tid * 17 + si];
      const float scv = logf(t) + g;   // logf(0) = -inf: never picked
      INSERT8(ts, tv, scv, t);
    }
    __syncthreads();
  }
#pragma unroll
  for (int j = 0; j < KTOP; ++j)
    pairs[(size_t)(sc * KTOP + j) * ROWS + r] = make_float2(ts[j], tv[j]);
}

// Kernel 2: merge NS partial top-8s per row -> pooled[r] = sum of top-8 values.
// 4 merger threads per row (contiguous chunk ranges preserve tie order),
// final merge via LDS. grid ROWS/64; block 256.
__global__ __launch_bounds__(256) void topk_merge(
    const float2* __restrict__ pairs, float* __restrict__ pooled, int NS) {
  __shared__ float2 ls[64 * 4 * KTOP];  // 16 KB
  const int tid  = threadIdx.x;
  const int rloc = tid >> 2;
  const int q    = tid & 3;
  const int r    = blockIdx.x * 64 + rloc;

  float ts[KTOP], tv[KTOP];
#pragma unroll
  for (int i = 0; i < KTOP; ++i) { ts[i] = -INFINITY; tv[i] = 0.0f; }

  const int per = (NS + 3) >> 2;
  const int c0  = q * per;
  const int c1  = (c0 + per < NS) ? (c0 + per) : NS;
  for (int c = c0; c < c1; ++c) {
#pragma unroll
    for (int j = 0; j < KTOP; ++j) {
      const float2 p = pairs[(size_t)(c * KTOP + j) * ROWS + r];
      INSERT8(ts, tv, p.x, p.y);
    }
  }
#pragma unroll
  for (int j = 0; j < KTOP; ++j)
    ls[(rloc * 4 + q) * KTOP + j] = make_float2(ts[j], tv[j]);
  __syncthreads();
  if (q == 0) {
    for (int qq = 1; qq < 4; ++qq) {
#pragma unroll
      for (int j = 0; j < KTOP; ++j) {
        const float2 p = ls[(rloc * 4 + qq) * KTOP + j];
        INSERT8(ts, tv, p.x, p.y);
      }
    }
    float sum = 0.0f;
#pragma unroll
    for (int j = 0; j < KTOP; ++j) sum += tv[j];
    // all-zero rows: every slot stayed (-inf, 0) -> sum 0, matching reference
    pooled[r] = sum;
  }
}

// Kernel 3: out[b][j] = tanh(sum_h pooled[b][h] * W[j][h] + bias[j]).
// grid 64; block 256 (4 waves x 4 j each). W read once, coalesced.
__global__ __launch_bounds__(256) void linear_tanh(
    const float* __restrict__ pooled, const float* __restrict__ W,
    const float* __restrict__ bias, float* __restrict__ out) {
  __shared__ float lp[ROWS];  // 32 KB: full pooled
  const int tid = threadIdx.x;
  for (int i = tid; i < ROWS / 4; i += 256)
    ((float4*)lp)[i] = ((const float4*)pooled)[i];
  __syncthreads();

  const int wave = tid >> 6;
  const int lane = tid & 63;
#pragma unroll
  for (int jj = 0; jj < 4; ++jj) {
    const int j = blockIdx.x * 16 + wave * 4 + jj;
    float acc[BB];
#pragma unroll
    for (int bb = 0; bb < BB; ++bb) acc[bb] = 0.0f;
    for (int k = 0; k < HH; k += 64) {
      const float w = W[(size_t)j * HH + k + lane];
#pragma unroll
      for (int bb = 0; bb < BB; ++bb) acc[bb] += w * lp[bb * HH + k + lane];
    }
#pragma unroll
    for (int bb = 0; bb < BB; ++bb) {
      float a = acc[bb];
      for (int off = 32; off > 0; off >>= 1) a += __shfl_down(a, off, 64);
      if (lane == 0) out[(size_t)bb * HH + j] = tanhf(a + bias[j]);
    }
  }
}

extern "C" void kernel_launch(void* const* d_in, const int* in_sizes, int n_in,
                              void* d_out, int out_size, void* d_ws, size_t ws_size,
                              hipStream_t stream) {
  const float* hidden = (const float*)d_in[0];
  const float* gumbel = (const float*)d_in[1];
  const float* W      = (const float*)d_in[2];
  const float* bias   = (const float*)d_in[3];
  float* out          = (float*)d_out;

  // pick NS (s-chunks) to fit workspace: pairs (NS*8*ROWS float2) + pooled
  int NS = 32;
  while (NS > 1) {
    const size_t need = (size_t)NS * KTOP * ROWS * sizeof(float2)
                        + (size_t)ROWS * sizeof(float);
    if (need <= ws_size) break;
    NS >>= 1;
  }
  float2* pairs = (float2*)d_ws;
  float*  pooled = (float*)((char*)d_ws
                   + (size_t)NS * KTOP * ROWS * sizeof(float2));
  const int SC = SS / NS;

  topk_partial<<<dim3(NS, 32), dim3(256), 0, stream>>>(hidden, gumbel, pairs, SC);
  topk_merge<<<dim3(ROWS / 64), dim3(256), 0, stream>>>(pairs, pooled, NS);
  linear_tanh<<<dim3(HH / 16), dim3(256), 0, stream>>>(pooled, W, bias, out);
}

// Round 2
// 339.721 us; speedup vs baseline: 1.0516x; 1.0516x over previous
//
#include <hip/hip_runtime.h>
#include <math.h>

#define BB 8
#define SS 4096
#define HH 1024
#define ROWS (BB * HH)   // 8192
#define KTOP 8

// Sorted-descending top-8 insert; strict > keeps earlier (lower s) on ties,
// matching lax.top_k's lowest-index tie-break.
#define INSERT8(TS, TV, SCV, VALV) do {                                   \
    if ((SCV) > TS[7]) {                                                  \
      TS[7] = (SCV); TV[7] = (VALV);                                      \
      _Pragma("unroll")                                                   \
      for (int _i = 7; _i > 0; --_i) {                                    \
        if (TS[_i] > TS[_i - 1]) {                                        \
          float _t = TS[_i]; TS[_i] = TS[_i - 1]; TS[_i - 1] = _t;        \
          float _v = TV[_i]; TV[_i] = TV[_i - 1]; TV[_i - 1] = _v;        \
        }                                                                 \
      }                                                                   \
    }                                                                     \
  } while (0)

// Kernel 1: per-(row, s-chunk) partial top-8 of log(relu(h)) + gumbel.
// NO LDS, NO barriers. Thread tid owns row r = rb*256+tid (lane <-> h), so
// hidden[(b*SS+s)*HH + h0 + tid] is perfectly coalesced at uniform s, and
// gumbel[r][s..s+3] float4 loads are per-thread contiguous (L1/L2 line reuse,
// 1x HBM traffic). Occupancy limited only by VGPRs.
// pairs layout: [(chunk*8 + j) * ROWS + r]  (coalesced write & merge-read)
__global__ __launch_bounds__(256) void topk_partial(
    const float* __restrict__ hidden, const float* __restrict__ gumbel,
    float2* __restrict__ pairs, int SC) {
  const int tid = threadIdx.x;
  const int sc  = blockIdx.x;
  const int rb  = blockIdx.y;
  const int r   = rb * 256 + tid;
  const int b   = rb >> 2;            // 256 rows never straddle a b boundary
  const int h0  = (rb & 3) << 8;
  const int s0  = sc * SC;

  const float* __restrict__ hcol = hidden + (size_t)b * SS * HH + h0 + tid;
  const float* __restrict__ grow = gumbel + (size_t)r * SS;

  float ts[KTOP], tv[KTOP];
#pragma unroll
  for (int i = 0; i < KTOP; ++i) { ts[i] = -INFINITY; tv[i] = 0.0f; }

  for (int ss = 0; ss < SC; ss += 8) {
    const int s = s0 + ss;
    // 2x float4 gumbel (32B per thread: full 64B-line utilization over 2 iters)
    const float4 g0 = *(const float4*)&grow[s];
    const float4 g1 = *(const float4*)&grow[s + 4];
    // 8 coalesced hidden loads (1KB per 256-thread group each)
    const float* __restrict__ hp = hcol + (size_t)s * HH;
    float h[8];
#pragma unroll
    for (int i = 0; i < 8; ++i) h[i] = hp[(size_t)i * HH];
    const float g[8] = {g0.x, g0.y, g0.z, g0.w, g1.x, g1.y, g1.z, g1.w};
#pragma unroll
    for (int i = 0; i < 8; ++i) {
      const float t   = fmaxf(h[i], 0.0f);
      const float scv = logf(t) + g[i];   // logf(0) = -inf: never picked
      INSERT8(ts, tv, scv, t);
    }
  }
#pragma unroll
  for (int j = 0; j < KTOP; ++j)
    pairs[(size_t)(sc * KTOP + j) * ROWS + r] = make_float2(ts[j], tv[j]);
}

// Kernel 2: merge NS partial top-8s per row -> pooled[r] = sum of top-8 values.
// 4 merger threads per row (contiguous chunk ranges preserve tie order),
// final merge via LDS. grid ROWS/64; block 256.
__global__ __launch_bounds__(256) void topk_merge(
    const float2* __restrict__ pairs, float* __restrict__ pooled, int NS) {
  __shared__ float2 ls[64 * 4 * KTOP];  // 16 KB
  const int tid  = threadIdx.x;
  const int rloc = tid >> 2;
  const int q    = tid & 3;
  const int r    = blockIdx.x * 64 + rloc;

  float ts[KTOP], tv[KTOP];
#pragma unroll
  for (int i = 0; i < KTOP; ++i) { ts[i] = -INFINITY; tv[i] = 0.0f; }

  const int per = (NS + 3) >> 2;
  const int c0  = q * per;
  const int c1  = (c0 + per < NS) ? (c0 + per) : NS;
  for (int c = c0; c < c1; ++c) {
#pragma unroll
    for (int j = 0; j < KTOP; ++j) {
      const float2 p = pairs[(size_t)(c * KTOP + j) * ROWS + r];
      INSERT8(ts, tv, p.x, p.y);
    }
  }
#pragma unroll
  for (int j = 0; j < KTOP; ++j)
    ls[(rloc * 4 + q) * KTOP + j] = make_float2(ts[j], tv[j]);
  __syncthreads();
  if (q == 0) {
    for (int qq = 1; qq < 4; ++qq) {
#pragma unroll
      for (int j = 0; j < KTOP; ++j) {
        const float2 p = ls[(rloc * 4 + qq) * KTOP + j];
        INSERT8(ts, tv, p.x, p.y);
      }
    }
    float sum = 0.0f;
#pragma unroll
    for (int j = 0; j < KTOP; ++j) sum += tv[j];
    // all-zero rows: every slot stayed (-inf, 0) -> sum 0, matching reference
    pooled[r] = sum;
  }
}

// Kernel 3: out[b][j] = tanh(sum_h pooled[b][h] * W[j][h] + bias[j]).
// grid 256 blocks x 4 waves; one wave per output column j. W read once via
// float4 (1KB per wave-instr); pooled staged to LDS; shuffle-reduce over lanes.
__global__ __launch_bounds__(256) void linear_tanh(
    const float* __restrict__ pooled, const float* __restrict__ W,
    const float* __restrict__ bias, float* __restrict__ out) {
  __shared__ float lp[ROWS];  // 32 KB: full pooled
  const int tid = threadIdx.x;
#pragma unroll
  for (int i = 0; i < ROWS / 4 / 256; ++i)
    ((float4*)lp)[i * 256 + tid] = ((const float4*)pooled)[i * 256 + tid];
  __syncthreads();

  const int wave = tid >> 6;
  const int lane = tid & 63;
  const int j = blockIdx.x * 4 + wave;

  float acc[BB];
#pragma unroll
  for (int bb = 0; bb < BB; ++bb) acc[bb] = 0.0f;
#pragma unroll
  for (int k0 = 0; k0 < HH; k0 += 256) {
    const float4 w4 = *(const float4*)&W[(size_t)j * HH + k0 + lane * 4];
#pragma unroll
    for (int bb = 0; bb < BB; ++bb) {
      const float4 p4 = *(const float4*)&lp[bb * HH + k0 + lane * 4];
      acc[bb] += w4.x * p4.x + w4.y * p4.y + w4.z * p4.z + w4.w * p4.w;
    }
  }
#pragma unroll
  for (int bb = 0; bb < BB; ++bb) {
    float a = acc[bb];
    for (int off = 32; off > 0; off >>= 1) a += __shfl_down(a, off, 64);
    if (lane == 0) out[(size_t)bb * HH + j] = tanhf(a + bias[j]);
  }
}

extern "C" void kernel_launch(void* const* d_in, const int* in_sizes, int n_in,
                              void* d_out, int out_size, void* d_ws, size_t ws_size,
                              hipStream_t stream) {
  const float* hidden = (const float*)d_in[0];
  const float* gumbel = (const float*)d_in[1];
  const float* W      = (const float*)d_in[2];
  const float* bias   = (const float*)d_in[3];
  float* out          = (float*)d_out;

  // pick NS (s-chunks) to fit workspace: pairs (NS*8*ROWS float2) + pooled
  int NS = 32;
  while (NS > 1) {
    const size_t need = (size_t)NS * KTOP * ROWS * sizeof(float2)
                        + (size_t)ROWS * sizeof(float);
    if (need <= ws_size) break;
    NS >>= 1;
  }
  float2* pairs = (float2*)d_ws;
  float*  pooled = (float*)((char*)d_ws
                   + (size_t)NS * KTOP * ROWS * sizeof(float2));
  const int SC = SS / NS;

  topk_partial<<<dim3(NS, 32), dim3(256), 0, stream>>>(hidden, gumbel, pairs, SC);
  topk_merge<<<dim3(ROWS / 64), dim3(256), 0, stream>>>(pairs, pooled, NS);
  linear_tanh<<<dim3(HH / 4), dim3(256), 0, stream>>>(pooled, W, bias, out);
}

// Round 3
// 321.050 us; speedup vs baseline: 1.1128x; 1.0582x over previous
//
#include <hip/hip_runtime.h>
#include <math.h>

#define BB 8
#define SS 4096
#define HH 1024
#define ROWS (BB * HH)   // 8192
#define KTOP 8
#define NS 32            // s-chunks; pairs ws = ROWS*NS*8*8B = 16.8 MB (fits, proven R1/R2)
#define SC (SS / NS)     // 128 s per chunk
#define SCW (SC / 4)     // 32 s per thread (4 wave-subchunks per block)
#define NB (SCW / 8)     // 4 batches of 8

// Sorted-descending top-8 insert; strict > keeps earlier (lower s) on ties,
// matching lax.top_k's lowest-index tie-break.
#define INSERT8(TS, TV, SCV, VALV) do {                                   \
    if ((SCV) > TS[7]) {                                                  \
      TS[7] = (SCV); TV[7] = (VALV);                                      \
      _Pragma("unroll")                                                   \
      for (int _i = 7; _i > 0; --_i) {                                    \
        if (TS[_i] > TS[_i - 1]) {                                        \
          float _t = TS[_i]; TS[_i] = TS[_i - 1]; TS[_i - 1] = _t;        \
          float _v = TV[_i]; TV[_i] = TV[_i - 1]; TV[_i - 1] = _v;        \
        }                                                                 \
      }                                                                   \
    }                                                                     \
  } while (0)

// Kernel 1: per-(row, s-chunk) top-8 of log(relu(h)) + gumbel.
// Block = 64 rows x 4 wave-subchunks (thread sequence = 32 elems), grid
// (NS, ROWS/64) = 4096 blocks = 16384 waves (2x device capacity). Explicit
// next-batch prefetch pipelines loads over the insert compute. Subchunk
// top-8s tree-merged in LDS (ascending s order preserves tie-break).
// pairs layout: [r][c][j] float2 -> merge kernel reads are contiguous.
__global__ __launch_bounds__(256) void topk_partial(
    const float* __restrict__ hidden, const float* __restrict__ gumbel,
    float2* __restrict__ pairs) {
  __shared__ float2 lst[256 * 9];   // [slot=w*64+rl][j], pad 8->9 kills conflicts

  const int tid = threadIdx.x;
  const int rl  = tid & 63;         // local row (lane)
  const int w   = tid >> 6;         // wave = s-subchunk
  const int sc  = blockIdx.x;
  const int rb  = blockIdx.y;       // 64-row block
  const int r   = rb * 64 + rl;
  const int b   = rb >> 4;          // 64-row blocks never straddle a b
  const int h0  = (rb & 15) << 6;
  const int s_base = sc * SC + w * SCW;

  const float* __restrict__ hcol = hidden + ((size_t)b * SS) * HH + h0 + rl;
  const float4* __restrict__ gp =
      (const float4*)(gumbel + (size_t)r * SS + s_base);

  float ts[KTOP], tv[KTOP];
#pragma unroll
  for (int i = 0; i < KTOP; ++i) { ts[i] = -INFINITY; tv[i] = 0.0f; }

  // software pipeline: batch of 8 elements, prefetch depth 1
  float4 ga = gp[0], gb = gp[1];
  float hb[8];
  {
    const float* __restrict__ hp = hcol + (size_t)s_base * HH;
#pragma unroll
    for (int i = 0; i < 8; ++i) hb[i] = hp[(size_t)i * HH];
  }
#pragma unroll
  for (int k = 0; k < NB; ++k) {
    float4 gna, gnb; float hn[8];
    if (k + 1 < NB) {
      gna = gp[2 * k + 2]; gnb = gp[2 * k + 3];
      const float* __restrict__ hp = hcol + (size_t)(s_base + 8 * (k + 1)) * HH;
#pragma unroll
      for (int i = 0; i < 8; ++i) hn[i] = hp[(size_t)i * HH];
    }
    const float g[8] = {ga.x, ga.y, ga.z, ga.w, gb.x, gb.y, gb.z, gb.w};
#pragma unroll
    for (int i = 0; i < 8; ++i) {
      const float t   = fmaxf(hb[i], 0.0f);
      const float scv = logf(t) + g[i];   // logf(0) = -inf: never picked
      INSERT8(ts, tv, scv, t);
    }
    if (k + 1 < NB) {
      ga = gna; gb = gnb;
#pragma unroll
      for (int i = 0; i < 8; ++i) hb[i] = hn[i];
    }
  }

  // publish per-subchunk top-8
#pragma unroll
  for (int j = 0; j < KTOP; ++j)
    lst[(w * 64 + rl) * 9 + j] = make_float2(ts[j], tv[j]);
  __syncthreads();
  // stage 1: wave 0 merges list1 into its own (s-ascending: own is lower s),
  //          wave 2 merges list3 into its own
  if (w == 0 || w == 2) {
#pragma unroll
    for (int j = 0; j < KTOP; ++j) {
      const float2 p = lst[((w + 1) * 64 + rl) * 9 + j];
      INSERT8(ts, tv, p.x, p.y);
    }
    if (w == 2) {
#pragma unroll
      for (int j = 0; j < KTOP; ++j)
        lst[(2 * 64 + rl) * 9 + j] = make_float2(ts[j], tv[j]);
    }
  }
  __syncthreads();
  // stage 2: wave 0 merges merged23, writes row's chunk top-8 (contiguous 64B)
  if (w == 0) {
#pragma unroll
    for (int j = 0; j < KTOP; ++j) {
      const float2 p = lst[(2 * 64 + rl) * 9 + j];
      INSERT8(ts, tv, p.x, p.y);
    }
    float2* __restrict__ op = pairs + ((size_t)r * NS + sc) * KTOP;
#pragma unroll
    for (int j = 0; j < KTOP; ++j) op[j] = make_float2(ts[j], tv[j]);
  }
}

// Kernel 2: merge NS chunk top-8s per row -> pooled[r] = sum of top-8 values.
// 8 threads/row, each merges NS/8 contiguous chunks (512B contiguous reads),
// 3-level LDS tree (ascending group order preserves tie-break).
// grid ROWS/32 = 256 blocks; block 256.
__global__ __launch_bounds__(256) void topk_merge(
    const float2* __restrict__ pairs, float* __restrict__ pooled) {
  __shared__ float2 ls[256 * 9];    // [slot=rloc*8+q][j], padded
  const int tid  = threadIdx.x;
  const int rloc = tid >> 3;        // 0..31
  const int q    = tid & 7;         // chunk group
  const int r    = blockIdx.x * 32 + rloc;
  const int slot = rloc * 8 + q;

  float ts[KTOP], tv[KTOP];
#pragma unroll
  for (int i = 0; i < KTOP; ++i) { ts[i] = -INFINITY; tv[i] = 0.0f; }

  const int cpg = NS / 8;           // chunks per group
  const float4* __restrict__ p =
      (const float4*)(pairs + ((size_t)r * NS + q * cpg) * KTOP);
#pragma unroll
  for (int i = 0; i < cpg * KTOP / 2; ++i) {
    const float4 two = p[i];        // two (score,val) pairs
    INSERT8(ts, tv, two.x, two.y);
    INSERT8(ts, tv, two.z, two.w);
  }
#pragma unroll
  for (int j = 0; j < KTOP; ++j) ls[slot * 9 + j] = make_float2(ts[j], tv[j]);
  __syncthreads();
  if ((q & 1) == 0) {               // level 1: (0,1)(2,3)(4,5)(6,7)
#pragma unroll
    for (int j = 0; j < KTOP; ++j) {
      const float2 pp = ls[(slot + 1) * 9 + j];
      INSERT8(ts, tv, pp.x, pp.y);
    }
#pragma unroll
    for (int j = 0; j < KTOP; ++j) ls[slot * 9 + j] = make_float2(ts[j], tv[j]);
  }
  __syncthreads();
  if ((q & 3) == 0) {               // level 2: (0,2)(4,6)
#pragma unroll
    for (int j = 0; j < KTOP; ++j) {
      const float2 pp = ls[(slot + 2) * 9 + j];
      INSERT8(ts, tv, pp.x, pp.y);
    }
#pragma unroll
    for (int j = 0; j < KTOP; ++j) ls[slot * 9 + j] = make_float2(ts[j], tv[j]);
  }
  __syncthreads();
  if (q == 0) {                     // level 3: (0,4) -> final sum
#pragma unroll
    for (int j = 0; j < KTOP; ++j) {
      const float2 pp = ls[(slot + 4) * 9 + j];
      INSERT8(ts, tv, pp.x, pp.y);
    }
    float sum = 0.0f;
#pragma unroll
    for (int j = 0; j < KTOP; ++j) sum += tv[j];
    // all-zero rows: every slot stayed (-inf, 0) -> sum 0, matching reference
    pooled[r] = sum;
  }
}

// Kernel 3: out[b][j] = tanh(sum_h pooled[b][h] * W[j][h] + bias[j]).
// grid 256 blocks x 4 waves; one wave per output column j. W read once via
// float4 (1KB per wave-instr); pooled staged to LDS; shuffle-reduce over lanes.
__global__ __launch_bounds__(256) void linear_tanh(
    const float* __restrict__ pooled, const float* __restrict__ W,
    const float* __restrict__ bias, float* __restrict__ out) {
  __shared__ float lp[ROWS];  // 32 KB: full pooled
  const int tid = threadIdx.x;
#pragma unroll
  for (int i = 0; i < ROWS / 4 / 256; ++i)
    ((float4*)lp)[i * 256 + tid] = ((const float4*)pooled)[i * 256 + tid];
  __syncthreads();

  const int wave = tid >> 6;
  const int lane = tid & 63;
  const int j = blockIdx.x * 4 + wave;

  float acc[BB];
#pragma unroll
  for (int bb = 0; bb < BB; ++bb) acc[bb] = 0.0f;
#pragma unroll
  for (int k0 = 0; k0 < HH; k0 += 256) {
    const float4 w4 = *(const float4*)&W[(size_t)j * HH + k0 + lane * 4];
#pragma unroll
    for (int bb = 0; bb < BB; ++bb) {
      const float4 p4 = *(const float4*)&lp[bb * HH + k0 + lane * 4];
      acc[bb] += w4.x * p4.x + w4.y * p4.y + w4.z * p4.z + w4.w * p4.w;
    }
  }
#pragma unroll
  for (int bb = 0; bb < BB; ++bb) {
    float a = acc[bb];
    for (int off = 32; off > 0; off >>= 1) a += __shfl_down(a, off, 64);
    if (lane == 0) out[(size_t)bb * HH + j] = tanhf(a + bias[j]);
  }
}

extern "C" void kernel_launch(void* const* d_in, const int* in_sizes, int n_in,
                              void* d_out, int out_size, void* d_ws, size_t ws_size,
                              hipStream_t stream) {
  const float* hidden = (const float*)d_in[0];
  const float* gumbel = (const float*)d_in[1];
  const float* W      = (const float*)d_in[2];
  const float* bias   = (const float*)d_in[3];
  float* out          = (float*)d_out;

  float2* pairs  = (float2*)d_ws;
  float*  pooled = (float*)((char*)d_ws
                   + (size_t)ROWS * NS * KTOP * sizeof(float2));

  topk_partial<<<dim3(NS, ROWS / 64), dim3(256), 0, stream>>>(hidden, gumbel, pairs);
  topk_merge<<<dim3(ROWS / 32), dim3(256), 0, stream>>>(pairs, pooled);
  linear_tanh<<<dim3(HH / 4), dim3(256), 0, stream>>>(pooled, W, bias, out);
}